// Round 10
// baseline (593.619 us; speedup 1.0000x reference)
//
#include <hip/hip_runtime.h>

#define DIN 55
#define HD 128
#define EB 8192          // edges per partition block
#define NBKT 512         // radix buckets (dst >> 8)

typedef unsigned short u16;
typedef unsigned int u32;
typedef short short8 __attribute__((ext_vector_type(8)));
typedef float f32x4 __attribute__((ext_vector_type(4)));

// ---- bf16 helpers ----
__device__ __forceinline__ u16 f2bf(float f) {
    u32 u = __float_as_uint(f);
    u32 r = (u + 0x7FFFu + ((u >> 16) & 1u)) >> 16;
    return (u16)r;
}
__device__ __forceinline__ float bfLo(u32 u) { return __uint_as_float(u << 16); }
__device__ __forceinline__ float bfHi(u32 u) { return __uint_as_float(u & 0xFFFF0000u); }

// ---------------- utility ----------------
__global__ void zero_f32_kernel(float* p, int n) {
    int i = blockIdx.x * blockDim.x + threadIdx.x;
    if (i < n) p[i] = 0.f;
}

// ---------------- hierarchical inclusive scan (for histT only) ----------------
__global__ __launch_bounds__(256) void scan1_kernel(int* data, int* bsums, int n) {
    __shared__ int sT[256];
    int t = threadIdx.x;
    int base = blockIdx.x * 1024 + t * 4;
    int v0 = (base + 0 < n) ? data[base + 0] : 0;
    int v1 = (base + 1 < n) ? data[base + 1] : 0;
    int v2 = (base + 2 < n) ? data[base + 2] : 0;
    int v3 = (base + 3 < n) ? data[base + 3] : 0;
    v1 += v0; v2 += v1; v3 += v2;
    sT[t] = v3;
    __syncthreads();
    for (int off = 1; off < 256; off <<= 1) {
        int x = (t >= off) ? sT[t - off] : 0;
        __syncthreads();
        sT[t] += x;
        __syncthreads();
    }
    int excl = (t == 0) ? 0 : sT[t - 1];
    if (base + 0 < n) data[base + 0] = v0 + excl;
    if (base + 1 < n) data[base + 1] = v1 + excl;
    if (base + 2 < n) data[base + 2] = v2 + excl;
    if (base + 3 < n) data[base + 3] = v3 + excl;
    if (t == 255) bsums[blockIdx.x] = sT[255];
}
__global__ __launch_bounds__(1024) void scan2_kernel(int* bsums, int nb) {
    __shared__ int s[1024];
    int t = threadIdx.x;
    int v = (t < nb) ? bsums[t] : 0;
    s[t] = v;
    __syncthreads();
    for (int o = 1; o < 1024; o <<= 1) {
        int x = (t >= o) ? s[t - o] : 0;
        __syncthreads();
        s[t] += x;
        __syncthreads();
    }
    if (t < nb) bsums[t] = s[t] - v;   // exclusive
}
__global__ void scan3_kernel(int* data, const int* __restrict__ bsums, int n) {
    int i = blockIdx.x * blockDim.x + threadIdx.x;
    if (i < n) data[i] += bsums[i >> 10];
}

// ---------------- radix partition of edges by dst>>8 ----------------
__global__ __launch_bounds__(256) void rhist_kernel(const int* __restrict__ dst,
                                                    int* __restrict__ histT, int E, int nB) {
    __shared__ int hh[NBKT];
    int t = threadIdx.x;
    for (int i = t; i < NBKT; i += 256) hh[i] = 0;
    __syncthreads();
    int base = blockIdx.x * EB;
    int end = min(base + EB, E);
    for (int i = base + t; i < end; i += 256) atomicAdd(&hh[dst[i] >> 8], 1);
    __syncthreads();
    for (int b = t; b < NBKT; b += 256) histT[b * nB + blockIdx.x] = hh[b];
}

// ticket from scanned histT directly; LDS atomics only
__global__ __launch_bounds__(256) void rpos_kernel(const int* __restrict__ src,
                                                   const int* __restrict__ dst,
                                                   const int* __restrict__ scanned,
                                                   u32* __restrict__ bpairs, int E, int nB) {
    __shared__ int cur[NBKT];
    int t = threadIdx.x;
    for (int b = t; b < NBKT; b += 256) {
        int idx = b * nB + blockIdx.x;
        cur[b] = (idx == 0) ? 0 : scanned[idx - 1];
    }
    __syncthreads();
    int base = blockIdx.x * EB;
    int end = min(base + EB, E);
    for (int i = base + t; i < end; i += 256) {
        int d = dst[i];
        int p = atomicAdd(&cur[d >> 8], 1);
        bpairs[p] = ((u32)src[i] << 8) | (u32)(d & 255);
    }
}

// fused per-bucket: count -> local scan -> write off -> scatter esrc (all LDS)
__global__ __launch_bounds__(256) void bfinal_kernel(const u32* __restrict__ bpairs,
                                                     const int* __restrict__ scanned,
                                                     int* __restrict__ off,
                                                     int* __restrict__ esrc, int N, int nB) {
    __shared__ int cnt[256];
    __shared__ int sc[256];
    __shared__ int cur[256];
    int b = blockIdx.x, t = threadIdx.x;
    int lo = (b == 0) ? 0 : scanned[b * nB - 1];
    int hi = scanned[(b + 1) * nB - 1];
    cnt[t] = 0;
    __syncthreads();
    for (int i = lo + t; i < hi; i += 256) atomicAdd(&cnt[bpairs[i] & 255u], 1);
    __syncthreads();
    int v = cnt[t];
    sc[t] = v;
    __syncthreads();
    for (int o = 1; o < 256; o <<= 1) {
        int x = (t >= o) ? sc[t - o] : 0;
        __syncthreads();
        sc[t] += x;
        __syncthreads();
    }
    int incl = sc[t];
    int gbase = lo + incl - v;
    int n = b * 256 + t;
    if (n < N) off[n] = gbase;
    if (n == N - 1) off[N] = lo + incl;
    cur[t] = gbase;
    __syncthreads();
    for (int i = lo + t; i < hi; i += 256) {
        u32 p = bpairs[i];
        int q = atomicAdd(&cur[p & 255u], 1);
        esrc[q] = (int)(p >> 8);
    }
}

// ---------------- weight fragment pre-build: W (fp32 [k][j]) -> bf16 MFMA A-frags ----------------
// blockIdx.x = layer*2 + mat. Frag layout: wf[((ft*4+kc)*64+lane)*8 + i] = bf16(W[kc*32+(lane>>4)*8+i][ft*16+(lane&15)])
__global__ __launch_bounds__(512) void wfrag_kernel(const float* __restrict__ W1,
                                                    const float* __restrict__ W2,
                                                    u16* __restrict__ wf) {
    __shared__ u16 sW[128 * 136];
    int layer = blockIdx.x >> 1, mat = blockIdx.x & 1;
    const float* W = (mat ? W2 : W1) + (size_t)layer * HD * HD;
    u16* dst = wf + (size_t)blockIdx.x * 16384;
    int t = threadIdx.x;
    for (int c = t; c < 128 * 32; c += 512) {
        int k = c >> 5, j4 = c & 31;
        float4 wv = ((const float4*)W)[c];
        u32 p0 = (u32)f2bf(wv.x) | ((u32)f2bf(wv.y) << 16);
        u32 p1 = (u32)f2bf(wv.z) | ((u32)f2bf(wv.w) << 16);
        *(uint2*)&sW[k * 136 + j4 * 4] = make_uint2(p0, p1);
    }
    __syncthreads();
    for (int e = t; e < 2048; e += 512) {
        int lane = e & 63, g = e >> 6;       // g = ft*4 + kc
        int ft = g >> 2, kc = g & 3;
        int j = ft * 16 + (lane & 15);
        int k0 = kc * 32 + ((lane >> 4) << 3);
        short8 sv;
#pragma unroll
        for (int i = 0; i < 8; i++) sv[i] = (short)sW[(k0 + i) * 136 + j];
        *(short8*)&dst[e * 8] = sv;
    }
}

// ---------------- node projection: h = x @ W_fc + b_fc  (fp32 math, bf16 out) ----------------
__global__ __launch_bounds__(512, 2) void fc_kernel(const float* __restrict__ x,
                                                    const float* __restrict__ Wfc,
                                                    const float* __restrict__ bfc,
                                                    u16* __restrict__ h,
                                                    int N, int nTiles) {
    __shared__ float sW[DIN * HD];
    __shared__ float sX[128 * 56];
    for (int i = threadIdx.x; i < DIN * HD / 4; i += 512)
        ((float4*)sW)[i] = ((const float4*)Wfc)[i];
    const int c = threadIdx.x & 15;
    const int r = threadIdx.x >> 4;
    float4 bb0 = ((const float4*)bfc)[2 * c];
    float4 bb1 = ((const float4*)bfc)[2 * c + 1];

    for (int tile = blockIdx.x; tile < nTiles; tile += gridDim.x) {
        int base = tile * 128;
        int limit = min(128, N - base) * DIN;
        __syncthreads();
        for (int i = threadIdx.x; i < 128 * DIN; i += 512) {
            float v = (i < limit) ? x[(size_t)base * DIN + i] : 0.f;
            sX[(i / DIN) * 56 + (i % DIN)] = v;
        }
        __syncthreads();

        float acc[4][8];
#pragma unroll
        for (int ii = 0; ii < 4; ii++) {
            acc[ii][0] = bb0.x; acc[ii][1] = bb0.y; acc[ii][2] = bb0.z; acc[ii][3] = bb0.w;
            acc[ii][4] = bb1.x; acc[ii][5] = bb1.y; acc[ii][6] = bb1.z; acc[ii][7] = bb1.w;
        }
        const int n0 = r * 4;
#pragma unroll 5
        for (int k = 0; k < DIN; k++) {
            float4 w0 = *(const float4*)&sW[k * HD + c * 8];
            float4 w1 = *(const float4*)&sW[k * HD + c * 8 + 4];
            float av[4] = {sX[(n0 + 0) * 56 + k], sX[(n0 + 1) * 56 + k],
                           sX[(n0 + 2) * 56 + k], sX[(n0 + 3) * 56 + k]};
#pragma unroll
            for (int ii = 0; ii < 4; ii++) {
                acc[ii][0] += av[ii] * w0.x; acc[ii][1] += av[ii] * w0.y;
                acc[ii][2] += av[ii] * w0.z; acc[ii][3] += av[ii] * w0.w;
                acc[ii][4] += av[ii] * w1.x; acc[ii][5] += av[ii] * w1.y;
                acc[ii][6] += av[ii] * w1.z; acc[ii][7] += av[ii] * w1.w;
            }
        }
        int nvalid = N - base;
#pragma unroll
        for (int ii = 0; ii < 4; ii++) {
            if (n0 + ii < nvalid) {
                u32 p0 = (u32)f2bf(acc[ii][0]) | ((u32)f2bf(acc[ii][1]) << 16);
                u32 p1 = (u32)f2bf(acc[ii][2]) | ((u32)f2bf(acc[ii][3]) << 16);
                u32 p2 = (u32)f2bf(acc[ii][4]) | ((u32)f2bf(acc[ii][5]) << 16);
                u32 p3 = (u32)f2bf(acc[ii][6]) | ((u32)f2bf(acc[ii][7]) << 16);
                *(uint4*)&h[(size_t)(base + n0 + ii) * HD + c * 8] = make_uint4(p0, p1, p2, p3);
            }
        }
    }
}

// ---------------- fused GIN layer: gather -> MLP pair, one 128-node tile per block ----------------
// Wave w gathers nodes w*16..w*16+15 into sZ rows (agg lane pattern), then the block runs
// transposed GEMMs (A = weight frags from global table, B = activations b128 from sZ).
__global__ __launch_bounds__(512, 6) void gin_layer_kernel(const u16* __restrict__ h,
                                                           const int* __restrict__ off,
                                                           const int* __restrict__ esrc,
                                                           const u16* __restrict__ wf1,
                                                           const u16* __restrict__ wf2,
                                                           const float* __restrict__ b1,
                                                           const float* __restrict__ b2,
                                                           u16* __restrict__ out, int N) {
    __shared__ u16 sZ[128 * 136];        // gathered z -> z1 -> out-stage (row-major, pad 136)
    const int t = threadIdx.x;
    const int w = t >> 6, lane = t & 63;
    const int col = lane & 15;           // node-in-16 / feature-chunk selector
    const int fq = lane >> 4;            // feature quad / edge slot
    const int fbase = (w & 3) << 5;
    const int nbase = (w >> 2) << 6;

    // --- tile-invariant weight fragments: 16 coalesced b128 loads each ---
    short8 aw1[2][4], aw2[2][4];
#pragma unroll
    for (int ftl = 0; ftl < 2; ftl++) {
        int ft = ((w & 3) << 1) + ftl;
#pragma unroll
        for (int kc = 0; kc < 4; kc++) {
            aw1[ftl][kc] = *(const short8*)&wf1[((((ft << 2) + kc) << 6) + lane) * 8];
            aw2[ftl][kc] = *(const short8*)&wf2[((((ft << 2) + kc) << 6) + lane) * 8];
        }
    }
    float4 bias1v[2], bias2v[2];
#pragma unroll
    for (int ftl = 0; ftl < 2; ftl++) {
        bias1v[ftl] = *(const float4*)&b1[fbase + ftl * 16 + fq * 4];
        bias2v[ftl] = *(const float4*)&b2[fbase + ftl * 16 + fq * 4];
    }

    int base = blockIdx.x * 128;
    int nvalid = N - base;               // may exceed 128

    // --- gather phase: z[n] = h[n] + sum_e h[esrc[e]], written to sZ rows ---
    for (int ni = 0; ni < 16; ni++) {
        int n = (w << 4) + ni;
        int gn = base + n;
        if (gn >= N) break;
        int s0 = off[gn], s1 = off[gn + 1];
        float a0 = 0.f, a1 = 0.f, a2 = 0.f, a3 = 0.f, a4 = 0.f, a5 = 0.f, a6 = 0.f, a7 = 0.f;
        int e = s0;
#define ACC8(V) { a0 += bfLo(V.x); a1 += bfHi(V.x); a2 += bfLo(V.y); a3 += bfHi(V.y); \
                  a4 += bfLo(V.z); a5 += bfHi(V.z); a6 += bfLo(V.w); a7 += bfHi(V.w); }
        for (; e + 16 <= s1; e += 16) {
            int e0 = esrc[e + fq], e1 = esrc[e + 4 + fq];
            int e2 = esrc[e + 8 + fq], e3 = esrc[e + 12 + fq];
            uint4 v0 = *(const uint4*)&h[(size_t)e0 * HD + col * 8];
            uint4 v1 = *(const uint4*)&h[(size_t)e1 * HD + col * 8];
            uint4 v2 = *(const uint4*)&h[(size_t)e2 * HD + col * 8];
            uint4 v3 = *(const uint4*)&h[(size_t)e3 * HD + col * 8];
            ACC8(v0); ACC8(v1); ACC8(v2); ACC8(v3);
        }
        for (; e + 4 <= s1; e += 4) {
            int e0 = esrc[e + fq];
            uint4 v0 = *(const uint4*)&h[(size_t)e0 * HD + col * 8];
            ACC8(v0);
        }
        if (e + fq < s1) {
            int e0 = esrc[e + fq];
            uint4 v0 = *(const uint4*)&h[(size_t)e0 * HD + col * 8];
            ACC8(v0);
        }
        if (fq == 0) {                   // self term
            uint4 sv = *(const uint4*)&h[(size_t)gn * HD + col * 8];
            ACC8(sv);
        }
#undef ACC8
        a0 += __shfl_down(a0, 32); a1 += __shfl_down(a1, 32);
        a2 += __shfl_down(a2, 32); a3 += __shfl_down(a3, 32);
        a4 += __shfl_down(a4, 32); a5 += __shfl_down(a5, 32);
        a6 += __shfl_down(a6, 32); a7 += __shfl_down(a7, 32);
        a0 += __shfl_down(a0, 16); a1 += __shfl_down(a1, 16);
        a2 += __shfl_down(a2, 16); a3 += __shfl_down(a3, 16);
        a4 += __shfl_down(a4, 16); a5 += __shfl_down(a5, 16);
        a6 += __shfl_down(a6, 16); a7 += __shfl_down(a7, 16);
        if (fq == 0) {
            u32 p0 = (u32)f2bf(a0) | ((u32)f2bf(a1) << 16);
            u32 p1 = (u32)f2bf(a2) | ((u32)f2bf(a3) << 16);
            u32 p2 = (u32)f2bf(a4) | ((u32)f2bf(a5) << 16);
            u32 p3 = (u32)f2bf(a6) | ((u32)f2bf(a7) << 16);
            *(uint4*)&sZ[n * 136 + col * 8] = make_uint4(p0, p1, p2, p3);
        }
    }
    __syncthreads();                     // z tile complete

    // --- GEMM1: B-frags contiguous b128 from sZ ---
    short8 bx[4][4];
#pragma unroll
    for (int ntl = 0; ntl < 4; ntl++) {
        int n = nbase + ntl * 16 + col;
#pragma unroll
        for (int kc = 0; kc < 4; kc++)
            bx[ntl][kc] = *(const short8*)&sZ[n * 136 + kc * 32 + fq * 8];
    }
    f32x4 acc1[2][4];
#pragma unroll
    for (int ftl = 0; ftl < 2; ftl++)
#pragma unroll
        for (int ntl = 0; ntl < 4; ntl++) {
            acc1[ftl][ntl][0] = bias1v[ftl].x; acc1[ftl][ntl][1] = bias1v[ftl].y;
            acc1[ftl][ntl][2] = bias1v[ftl].z; acc1[ftl][ntl][3] = bias1v[ftl].w;
        }
#pragma unroll
    for (int ntl = 0; ntl < 4; ntl++)
#pragma unroll
        for (int kc = 0; kc < 4; kc++) {
            acc1[0][ntl] = __builtin_amdgcn_mfma_f32_16x16x32_bf16(aw1[0][kc], bx[ntl][kc], acc1[0][ntl], 0, 0, 0);
            acc1[1][ntl] = __builtin_amdgcn_mfma_f32_16x16x32_bf16(aw1[1][kc], bx[ntl][kc], acc1[1][ntl], 0, 0, 0);
        }
    __syncthreads();                     // all bx reads done
    // --- z1 = relu(acc1) row-major into sZ (b64: 4 consecutive features) ---
#pragma unroll
    for (int ftl = 0; ftl < 2; ftl++) {
        int f = fbase + ftl * 16 + fq * 4;
#pragma unroll
        for (int ntl = 0; ntl < 4; ntl++) {
            int n = nbase + ntl * 16 + col;
            float v0 = fmaxf(acc1[ftl][ntl][0], 0.f);
            float v1 = fmaxf(acc1[ftl][ntl][1], 0.f);
            float v2 = fmaxf(acc1[ftl][ntl][2], 0.f);
            float v3 = fmaxf(acc1[ftl][ntl][3], 0.f);
            u32 lo = (u32)f2bf(v0) | ((u32)f2bf(v1) << 16);
            u32 hi = (u32)f2bf(v2) | ((u32)f2bf(v3) << 16);
            *(uint2*)&sZ[n * 136 + f] = make_uint2(lo, hi);
        }
    }
    __syncthreads();                     // z1 ready
    // --- GEMM2 ---
    short8 bz[4][4];
#pragma unroll
    for (int ntl = 0; ntl < 4; ntl++) {
        int n = nbase + ntl * 16 + col;
#pragma unroll
        for (int kc = 0; kc < 4; kc++)
            bz[ntl][kc] = *(const short8*)&sZ[n * 136 + kc * 32 + fq * 8];
    }
    f32x4 acc2[2][4];
#pragma unroll
    for (int ftl = 0; ftl < 2; ftl++)
#pragma unroll
        for (int ntl = 0; ntl < 4; ntl++) {
            acc2[ftl][ntl][0] = bias2v[ftl].x; acc2[ftl][ntl][1] = bias2v[ftl].y;
            acc2[ftl][ntl][2] = bias2v[ftl].z; acc2[ftl][ntl][3] = bias2v[ftl].w;
        }
#pragma unroll
    for (int ntl = 0; ntl < 4; ntl++)
#pragma unroll
        for (int kc = 0; kc < 4; kc++) {
            acc2[0][ntl] = __builtin_amdgcn_mfma_f32_16x16x32_bf16(aw2[0][kc], bz[ntl][kc], acc2[0][ntl], 0, 0, 0);
            acc2[1][ntl] = __builtin_amdgcn_mfma_f32_16x16x32_bf16(aw2[1][kc], bz[ntl][kc], acc2[1][ntl], 0, 0, 0);
        }
    __syncthreads();                     // all bz reads done
    // --- stage acc2 -> sZ row-major ---
#pragma unroll
    for (int ftl = 0; ftl < 2; ftl++) {
        int f = fbase + ftl * 16 + fq * 4;
#pragma unroll
        for (int ntl = 0; ntl < 4; ntl++) {
            int n = nbase + ntl * 16 + col;
            u32 lo = (u32)f2bf(acc2[ftl][ntl][0]) | ((u32)f2bf(acc2[ftl][ntl][1]) << 16);
            u32 hi = (u32)f2bf(acc2[ftl][ntl][2]) | ((u32)f2bf(acc2[ftl][ntl][3]) << 16);
            *(uint2*)&sZ[n * 136 + f] = make_uint2(lo, hi);
        }
    }
    __syncthreads();
    // --- coalesced store ---
#pragma unroll
    for (int i = 0; i < 4; i++) {
        int c = t + 512 * i;
        int n = c >> 4, k8 = c & 15;
        if (n < nvalid)
            *(uint4*)&out[((size_t)(base + n)) * HD + k8 * 8] =
                *(const uint4*)&sZ[n * 136 + k8 * 8];
    }
}

// ---------------- per-graph sum pool (bf16 in, fp32 atomics out) ----------------
__global__ __launch_bounds__(64) void pool_kernel(const u16* __restrict__ h,
                                                  const int* __restrict__ gid,
                                                  float* __restrict__ out, int N) {
    const int CH = 32;
    int j = threadIdx.x;
    int start = blockIdx.x * CH;
    if (start >= N) return;
    int end = min(start + CH, N);
    int cur = gid[start];
    float x0 = 0.f, x1 = 0.f;
    for (int n = start; n < end; n++) {
        int g = gid[n];
        if (g != cur) {
            atomicAdd(&out[(size_t)cur * HD + 2 * j], x0);
            atomicAdd(&out[(size_t)cur * HD + 2 * j + 1], x1);
            cur = g; x0 = 0.f; x1 = 0.f;
        }
        u32 v = *(const u32*)&h[(size_t)n * HD + j * 2];
        x0 += bfLo(v); x1 += bfHi(v);
    }
    atomicAdd(&out[(size_t)cur * HD + 2 * j], x0);
    atomicAdd(&out[(size_t)cur * HD + 2 * j + 1], x1);
}

extern "C" void kernel_launch(void* const* d_in, const int* in_sizes, int n_in,
                              void* d_out, int out_size, void* d_ws, size_t ws_size,
                              hipStream_t stream) {
    (void)n_in; (void)ws_size;
    const float* x   = (const float*)d_in[0];
    const float* Wfc = (const float*)d_in[1];
    const float* bfc = (const float*)d_in[2];
    const float* W1  = (const float*)d_in[3];
    const float* b1  = (const float*)d_in[4];
    const float* W2  = (const float*)d_in[5];
    const float* b2  = (const float*)d_in[6];
    const int* src   = (const int*)d_in[7];
    const int* dst   = (const int*)d_in[8];
    const int* gid   = (const int*)d_in[9];

    int N = in_sizes[0] / DIN;       // 100000
    int E = in_sizes[7];             // 1600000
    int nTiles = (N + 127) / 128;
    int nB = (E + EB - 1) / EB;      // partition blocks (196)
    int nScan2 = NBKT * nB;          // histT length
    int nb2 = (nScan2 + 1023) / 1024;

    // workspace layout (~65 MB)
    u16* buf0 = (u16*)d_ws;                       // N*128 bf16
    u16* buf1 = buf0 + (size_t)N * HD;            // N*128 bf16
    int* off    = (int*)(buf1 + (size_t)N * HD);  // N+1
    int* esrc   = off + (N + 1);                  // E
    int* bsums2 = esrc + E;                       // 256
    int* histT  = bsums2 + 256;                   // NBKT*nB
    u32* bpairs = (u32*)(histT + nScan2);         // E packed pairs
    u16* wf = (u16*)((((uintptr_t)(bpairs + E)) + 15) & ~(uintptr_t)15);  // 6*16384 bf16 frags

    // --- weight fragment tables (3 layers x 2 mats) ---
    wfrag_kernel<<<6, 512, 0, stream>>>(W1, W2, wf);

    // --- radix partition of edges by dst>>8 (no global atomics) ---
    rhist_kernel<<<nB, 256, 0, stream>>>(dst, histT, E, nB);
    scan1_kernel<<<nb2, 256, 0, stream>>>(histT, bsums2, nScan2);
    scan2_kernel<<<1, 1024, 0, stream>>>(bsums2, nb2);
    scan3_kernel<<<(nScan2 + 255) / 256, 256, 0, stream>>>(histT, bsums2, nScan2);
    rpos_kernel<<<nB, 256, 0, stream>>>(src, dst, histT, bpairs, E, nB);

    // --- fused per-node CSR offsets + scatter (per-bucket, LDS only) ---
    bfinal_kernel<<<NBKT, 256, 0, stream>>>(bpairs, histT, off, esrc, N, nB);

    // --- node projection (bf16 out) ---
    fc_kernel<<<512, 512, 0, stream>>>(x, Wfc, bfc, buf0, N, nTiles);

    // --- 3x fused GIN layers (ping-pong buffers) ---
    u16* cin = buf0;
    u16* cout = buf1;
    for (int l = 0; l < 3; l++) {
        gin_layer_kernel<<<nTiles, 512, 0, stream>>>(cin, off, esrc,
                                                     wf + (size_t)(2 * l) * 16384,
                                                     wf + (size_t)(2 * l + 1) * 16384,
                                                     b1 + (size_t)l * HD,
                                                     b2 + (size_t)l * HD, cout, N);
        u16* tmp = cin; cin = cout; cout = tmp;
    }

    // --- per-graph sum pooling (final result is in `cin` after last swap) ---
    zero_f32_kernel<<<(out_size + 255) / 256, 256, 0, stream>>>((float*)d_out, out_size);
    pool_kernel<<<(N + 31) / 32, 64, 0, stream>>>(cin, gid, (float*)d_out, N);
}

// Round 11
// 452.220 us; speedup vs baseline: 1.3127x; 1.3127x over previous
//
#include <hip/hip_runtime.h>

#define DIN 55
#define HD 128
#define EB 8192          // edges per partition block
#define NBKT 512         // radix buckets (dst >> 8)

typedef unsigned short u16;
typedef unsigned int u32;
typedef short short8 __attribute__((ext_vector_type(8)));
typedef float f32x4 __attribute__((ext_vector_type(4)));

// ---- bf16 helpers ----
__device__ __forceinline__ u16 f2bf(float f) {
    u32 u = __float_as_uint(f);
    u32 r = (u + 0x7FFFu + ((u >> 16) & 1u)) >> 16;
    return (u16)r;
}
__device__ __forceinline__ float bfLo(u32 u) { return __uint_as_float(u << 16); }
__device__ __forceinline__ float bfHi(u32 u) { return __uint_as_float(u & 0xFFFF0000u); }

// ---------------- utility ----------------
__global__ void zero_f32_kernel(float* p, int n) {
    int i = blockIdx.x * blockDim.x + threadIdx.x;
    if (i < n) p[i] = 0.f;
}

// ---------------- hierarchical inclusive scan (for histT only) ----------------
__global__ __launch_bounds__(256) void scan1_kernel(int* data, int* bsums, int n) {
    __shared__ int sT[256];
    int t = threadIdx.x;
    int base = blockIdx.x * 1024 + t * 4;
    int v0 = (base + 0 < n) ? data[base + 0] : 0;
    int v1 = (base + 1 < n) ? data[base + 1] : 0;
    int v2 = (base + 2 < n) ? data[base + 2] : 0;
    int v3 = (base + 3 < n) ? data[base + 3] : 0;
    v1 += v0; v2 += v1; v3 += v2;
    sT[t] = v3;
    __syncthreads();
    for (int off = 1; off < 256; off <<= 1) {
        int x = (t >= off) ? sT[t - off] : 0;
        __syncthreads();
        sT[t] += x;
        __syncthreads();
    }
    int excl = (t == 0) ? 0 : sT[t - 1];
    if (base + 0 < n) data[base + 0] = v0 + excl;
    if (base + 1 < n) data[base + 1] = v1 + excl;
    if (base + 2 < n) data[base + 2] = v2 + excl;
    if (base + 3 < n) data[base + 3] = v3 + excl;
    if (t == 255) bsums[blockIdx.x] = sT[255];
}
__global__ __launch_bounds__(1024) void scan2_kernel(int* bsums, int nb) {
    __shared__ int s[1024];
    int t = threadIdx.x;
    int v = (t < nb) ? bsums[t] : 0;
    s[t] = v;
    __syncthreads();
    for (int o = 1; o < 1024; o <<= 1) {
        int x = (t >= o) ? s[t - o] : 0;
        __syncthreads();
        s[t] += x;
        __syncthreads();
    }
    if (t < nb) bsums[t] = s[t] - v;   // exclusive
}
__global__ void scan3_kernel(int* data, const int* __restrict__ bsums, int n) {
    int i = blockIdx.x * blockDim.x + threadIdx.x;
    if (i < n) data[i] += bsums[i >> 10];
}

// ---------------- radix partition of edges by dst>>8 ----------------
__global__ __launch_bounds__(256) void rhist_kernel(const int* __restrict__ dst,
                                                    int* __restrict__ histT, int E, int nB) {
    __shared__ int hh[NBKT];
    int t = threadIdx.x;
    for (int i = t; i < NBKT; i += 256) hh[i] = 0;
    __syncthreads();
    int base = blockIdx.x * EB;
    int end = min(base + EB, E);
    for (int i = base + t; i < end; i += 256) atomicAdd(&hh[dst[i] >> 8], 1);
    __syncthreads();
    for (int b = t; b < NBKT; b += 256) histT[b * nB + blockIdx.x] = hh[b];
}

// ticket from scanned histT directly (exclusive base = scanned[flat-1]); LDS atomics only
__global__ __launch_bounds__(256) void rpos_kernel(const int* __restrict__ src,
                                                   const int* __restrict__ dst,
                                                   const int* __restrict__ scanned,
                                                   u32* __restrict__ bpairs, int E, int nB) {
    __shared__ int cur[NBKT];
    int t = threadIdx.x;
    for (int b = t; b < NBKT; b += 256) {
        int idx = b * nB + blockIdx.x;
        cur[b] = (idx == 0) ? 0 : scanned[idx - 1];
    }
    __syncthreads();
    int base = blockIdx.x * EB;
    int end = min(base + EB, E);
    for (int i = base + t; i < end; i += 256) {
        int d = dst[i];
        int p = atomicAdd(&cur[d >> 8], 1);
        bpairs[p] = ((u32)src[i] << 8) | (u32)(d & 255);
    }
}

// fused per-bucket: count -> local scan -> write off -> scatter esrc (all LDS)
__global__ __launch_bounds__(256) void bfinal_kernel(const u32* __restrict__ bpairs,
                                                     const int* __restrict__ scanned,
                                                     int* __restrict__ off,
                                                     int* __restrict__ esrc, int N, int nB) {
    __shared__ int cnt[256];
    __shared__ int sc[256];
    __shared__ int cur[256];
    int b = blockIdx.x, t = threadIdx.x;
    int lo = (b == 0) ? 0 : scanned[b * nB - 1];
    int hi = scanned[(b + 1) * nB - 1];
    cnt[t] = 0;
    __syncthreads();
    for (int i = lo + t; i < hi; i += 256) atomicAdd(&cnt[bpairs[i] & 255u], 1);
    __syncthreads();
    int v = cnt[t];
    sc[t] = v;
    __syncthreads();
    for (int o = 1; o < 256; o <<= 1) {
        int x = (t >= o) ? sc[t - o] : 0;
        __syncthreads();
        sc[t] += x;
        __syncthreads();
    }
    int incl = sc[t];
    int gbase = lo + incl - v;
    int n = b * 256 + t;
    if (n < N) off[n] = gbase;
    if (n == N - 1) off[N] = lo + incl;
    cur[t] = gbase;
    __syncthreads();
    for (int i = lo + t; i < hi; i += 256) {
        u32 p = bpairs[i];
        int q = atomicAdd(&cur[p & 255u], 1);
        esrc[q] = (int)(p >> 8);
    }
}

// ---------------- node projection: h = x @ W_fc + b_fc  (fp32 math, bf16 out) ----------------
__global__ __launch_bounds__(512, 2) void fc_kernel(const float* __restrict__ x,
                                                    const float* __restrict__ Wfc,
                                                    const float* __restrict__ bfc,
                                                    u16* __restrict__ h,
                                                    int N, int nTiles) {
    __shared__ float sW[DIN * HD];
    __shared__ float sX[128 * 56];
    for (int i = threadIdx.x; i < DIN * HD / 4; i += 512)
        ((float4*)sW)[i] = ((const float4*)Wfc)[i];
    const int c = threadIdx.x & 15;
    const int r = threadIdx.x >> 4;
    float4 bb0 = ((const float4*)bfc)[2 * c];
    float4 bb1 = ((const float4*)bfc)[2 * c + 1];

    for (int tile = blockIdx.x; tile < nTiles; tile += gridDim.x) {
        int base = tile * 128;
        int limit = min(128, N - base) * DIN;
        __syncthreads();
        for (int i = threadIdx.x; i < 128 * DIN; i += 512) {
            float v = (i < limit) ? x[(size_t)base * DIN + i] : 0.f;
            sX[(i / DIN) * 56 + (i % DIN)] = v;
        }
        __syncthreads();

        float acc[4][8];
#pragma unroll
        for (int ii = 0; ii < 4; ii++) {
            acc[ii][0] = bb0.x; acc[ii][1] = bb0.y; acc[ii][2] = bb0.z; acc[ii][3] = bb0.w;
            acc[ii][4] = bb1.x; acc[ii][5] = bb1.y; acc[ii][6] = bb1.z; acc[ii][7] = bb1.w;
        }
        const int n0 = r * 4;
#pragma unroll 5
        for (int k = 0; k < DIN; k++) {
            float4 w0 = *(const float4*)&sW[k * HD + c * 8];
            float4 w1 = *(const float4*)&sW[k * HD + c * 8 + 4];
            float av[4] = {sX[(n0 + 0) * 56 + k], sX[(n0 + 1) * 56 + k],
                           sX[(n0 + 2) * 56 + k], sX[(n0 + 3) * 56 + k]};
#pragma unroll
            for (int ii = 0; ii < 4; ii++) {
                acc[ii][0] += av[ii] * w0.x; acc[ii][1] += av[ii] * w0.y;
                acc[ii][2] += av[ii] * w0.z; acc[ii][3] += av[ii] * w0.w;
                acc[ii][4] += av[ii] * w1.x; acc[ii][5] += av[ii] * w1.y;
                acc[ii][6] += av[ii] * w1.z; acc[ii][7] += av[ii] * w1.w;
            }
        }
        int nvalid = N - base;
#pragma unroll
        for (int ii = 0; ii < 4; ii++) {
            if (n0 + ii < nvalid) {
                u32 p0 = (u32)f2bf(acc[ii][0]) | ((u32)f2bf(acc[ii][1]) << 16);
                u32 p1 = (u32)f2bf(acc[ii][2]) | ((u32)f2bf(acc[ii][3]) << 16);
                u32 p2 = (u32)f2bf(acc[ii][4]) | ((u32)f2bf(acc[ii][5]) << 16);
                u32 p3 = (u32)f2bf(acc[ii][6]) | ((u32)f2bf(acc[ii][7]) << 16);
                *(uint4*)&h[(size_t)(base + n0 + ii) * HD + c * 8] = make_uint4(p0, p1, p2, p3);
            }
        }
    }
}

// ---------------- edge aggregation: z[n] = h[n] + sum_{e} h[esrc[e]]  (bf16) ----------------
// one wave per node — maximal wave count for latency hiding (R10 showed fusing this kills it)
__global__ __launch_bounds__(256) void agg_kernel(const u16* __restrict__ h,
                                                  const int* __restrict__ off,
                                                  const int* __restrict__ esrc,
                                                  u16* __restrict__ z, int N) {
    int w = threadIdx.x >> 6, lane = threadIdx.x & 63;
    int n = blockIdx.x * 4 + w;
    if (n >= N) return;
    int s0 = off[n], s1 = off[n + 1];
    int g = lane >> 4, q = lane & 15;
    float a0 = 0.f, a1 = 0.f, a2 = 0.f, a3 = 0.f, a4 = 0.f, a5 = 0.f, a6 = 0.f, a7 = 0.f;
    int t = s0;
#define ACC8(V) { a0 += bfLo(V.x); a1 += bfHi(V.x); a2 += bfLo(V.y); a3 += bfHi(V.y); \
                  a4 += bfLo(V.z); a5 += bfHi(V.z); a6 += bfLo(V.w); a7 += bfHi(V.w); }
    for (; t + 16 <= s1; t += 16) {
        int e0 = esrc[t + g], e1 = esrc[t + 4 + g];
        int e2 = esrc[t + 8 + g], e3 = esrc[t + 12 + g];
        uint4 v0 = *(const uint4*)&h[(size_t)e0 * HD + q * 8];
        uint4 v1 = *(const uint4*)&h[(size_t)e1 * HD + q * 8];
        uint4 v2 = *(const uint4*)&h[(size_t)e2 * HD + q * 8];
        uint4 v3 = *(const uint4*)&h[(size_t)e3 * HD + q * 8];
        ACC8(v0); ACC8(v1); ACC8(v2); ACC8(v3);
    }
    for (; t + 4 <= s1; t += 4) {
        int e0 = esrc[t + g];
        uint4 v0 = *(const uint4*)&h[(size_t)e0 * HD + q * 8];
        ACC8(v0);
    }
    if (t + g < s1) {
        int e0 = esrc[t + g];
        uint4 v0 = *(const uint4*)&h[(size_t)e0 * HD + q * 8];
        ACC8(v0);
    }
    if (g == 0) {
        uint4 sv = *(const uint4*)&h[(size_t)n * HD + q * 8];
        ACC8(sv);
    }
#undef ACC8
    a0 += __shfl_down(a0, 32); a1 += __shfl_down(a1, 32);
    a2 += __shfl_down(a2, 32); a3 += __shfl_down(a3, 32);
    a4 += __shfl_down(a4, 32); a5 += __shfl_down(a5, 32);
    a6 += __shfl_down(a6, 32); a7 += __shfl_down(a7, 32);
    a0 += __shfl_down(a0, 16); a1 += __shfl_down(a1, 16);
    a2 += __shfl_down(a2, 16); a3 += __shfl_down(a3, 16);
    a4 += __shfl_down(a4, 16); a5 += __shfl_down(a5, 16);
    a6 += __shfl_down(a6, 16); a7 += __shfl_down(a7, 16);
    if (g == 0) {
        u32 p0 = (u32)f2bf(a0) | ((u32)f2bf(a1) << 16);
        u32 p1 = (u32)f2bf(a2) | ((u32)f2bf(a3) << 16);
        u32 p2 = (u32)f2bf(a4) | ((u32)f2bf(a5) << 16);
        u32 p3 = (u32)f2bf(a6) | ((u32)f2bf(a7) << 16);
        *(uint4*)&z[(size_t)n * HD + q * 8] = make_uint4(p0, p1, p2, p3);
    }
}

// ---------------- fused MLP pair (R8 version — best measured): ----------------
// Transposed GEMMs (A = weights, B = activations). Coalesced prefetch staging through sA,
// z1 via b64 row-major LDS, GEMM2 B-frags contiguous b128, coalesced epilogue through sZ.
__global__ __launch_bounds__(512, 2) void mlp_pair_kernel(const u16* __restrict__ in,
                                                          const float* __restrict__ W1,
                                                          const float* __restrict__ b1,
                                                          const float* __restrict__ W2,
                                                          const float* __restrict__ b2,
                                                          u16* __restrict__ out,
                                                          int N, int nTiles) {
    __shared__ u16 sB1[16384];           // W1 frags: [ft][kc][slot][8]
    __shared__ u16 sB2[16384];           // W2 frags
    __shared__ u16 sA[16384];            // activation frags: [nt][kc][slot][8]
    __shared__ u16 sZ[128 * 136];        // row-major activations [node][feature], pad 136

    const int t = threadIdx.x;
    // --- build weight frags (stage fp32->bf16 rows into sZ scratch, then fragment) ---
    for (int wsel = 0; wsel < 2; wsel++) {
        const float* W = wsel ? W2 : W1;
        u16* sB = wsel ? sB2 : sB1;
        __syncthreads();
        for (int c = t; c < 128 * 32; c += 512) {
            int k = c >> 5, j4 = c & 31;
            float4 wv = ((const float4*)W)[c];
            u32 p0 = (u32)f2bf(wv.x) | ((u32)f2bf(wv.y) << 16);
            u32 p1 = (u32)f2bf(wv.z) | ((u32)f2bf(wv.w) << 16);
            *(uint2*)&sZ[k * 136 + j4 * 4] = make_uint2(p0, p1);
        }
        __syncthreads();
        for (int e = t; e < 2048; e += 512) {
            int L = e & 63, gq = e >> 6;
            int ct = gq >> 2, kc = gq & 3;
            int j = ct * 16 + (L & 15);
            int k0 = kc * 32 + ((L >> 4) << 3);
            short8 sv;
#pragma unroll
            for (int i = 0; i < 8; i++) sv[i] = (short)sZ[(k0 + i) * 136 + j];
            int slot = L ^ (kc << 1);
            *(short8*)&sB[(((ct << 2) + kc) << 6 | slot) * 8] = sv;
        }
    }

    const int w = t >> 6, lane = t & 63;
    const int col = lane & 15;           // node within tile
    const int fq = lane >> 4;            // feature quad
    const int fbase = (w & 3) << 5;      // wave's 32 features (2 f-tiles)
    const int nbase = (w >> 2) << 6;     // wave's 64 nodes (4 n-tiles)
    float4 bias1v[2], bias2v[2];
#pragma unroll
    for (int ftl = 0; ftl < 2; ftl++) {
        bias1v[ftl] = *(const float4*)&b1[fbase + ftl * 16 + fq * 4];
        bias2v[ftl] = *(const float4*)&b2[fbase + ftl * 16 + fq * 4];
    }

    // prefetch tile 0
    uint4 pf[4];
    int tile = blockIdx.x;
    if (tile < nTiles) {
        int base = tile * 128;
        int limit = min(128, N - base) * 16;
#pragma unroll
        for (int i = 0; i < 4; i++) {
            int c = t + 512 * i;
            uint4 raw = make_uint4(0, 0, 0, 0);
            if (c < limit)
                raw = *(const uint4*)&in[((size_t)(base + (c >> 4))) * HD + (c & 15) * 8];
            pf[i] = raw;
        }
    }

    for (; tile < nTiles; tile += gridDim.x) {
        int base = tile * 128;
        int nvalid = N - base;
        __syncthreads();                 // S1: prev tile fully done (sA & sZ free)
#pragma unroll
        for (int i = 0; i < 4; i++) {    // regs -> sA (swizzled fragment slots)
            int c = t + 512 * i;
            int n = c >> 4, k8 = c & 15;
            int nt = n >> 4, kc = k8 >> 2;
            int L = ((k8 & 3) << 4) | (n & 15);
            int slot = L ^ (kc << 1);
            *(uint4*)&sA[(((nt << 2) + kc) << 6 | slot) * 8] = pf[i];
        }
        __syncthreads();                 // S2

        // issue next tile's prefetch (overlaps with both GEMMs)
        int ntile = tile + gridDim.x;
        if (ntile < nTiles) {
            int nb2 = ntile * 128;
            int nlimit = min(128, N - nb2) * 16;
#pragma unroll
            for (int i = 0; i < 4; i++) {
                int c = t + 512 * i;
                uint4 raw = make_uint4(0, 0, 0, 0);
                if (c < nlimit)
                    raw = *(const uint4*)&in[((size_t)(nb2 + (c >> 4))) * HD + (c & 15) * 8];
                pf[i] = raw;
            }
        }

        // --- GEMM1: D[feature][node] = W1^T (A) x in^T (B) ---
        short8 aw1[2][4];
#pragma unroll
        for (int ftl = 0; ftl < 2; ftl++) {
            int ft = ((w & 3) << 1) + ftl;
#pragma unroll
            for (int kc = 0; kc < 4; kc++)
                aw1[ftl][kc] = *(const short8*)&sB1[(((ft << 2) + kc) << 6 | (lane ^ (kc << 1))) * 8];
        }
        short8 bx[4][4];
#pragma unroll
        for (int ntl = 0; ntl < 4; ntl++) {
            int nt = ((w >> 2) << 2) + ntl;
#pragma unroll
            for (int kc = 0; kc < 4; kc++)
                bx[ntl][kc] = *(const short8*)&sA[(((nt << 2) + kc) << 6 | (lane ^ (kc << 1))) * 8];
        }
        f32x4 acc1[2][4];
#pragma unroll
        for (int ftl = 0; ftl < 2; ftl++)
#pragma unroll
            for (int ntl = 0; ntl < 4; ntl++) {
                acc1[ftl][ntl][0] = bias1v[ftl].x; acc1[ftl][ntl][1] = bias1v[ftl].y;
                acc1[ftl][ntl][2] = bias1v[ftl].z; acc1[ftl][ntl][3] = bias1v[ftl].w;
            }
#pragma unroll
        for (int ntl = 0; ntl < 4; ntl++)
#pragma unroll
            for (int kc = 0; kc < 4; kc++) {
                acc1[0][ntl] = __builtin_amdgcn_mfma_f32_16x16x32_bf16(aw1[0][kc], bx[ntl][kc], acc1[0][ntl], 0, 0, 0);
                acc1[1][ntl] = __builtin_amdgcn_mfma_f32_16x16x32_bf16(aw1[1][kc], bx[ntl][kc], acc1[1][ntl], 0, 0, 0);
            }
        // --- write z1 = relu(acc1) row-major into sZ via b64 (4 consecutive features) ---
#pragma unroll
        for (int ftl = 0; ftl < 2; ftl++) {
            int f = fbase + ftl * 16 + fq * 4;
#pragma unroll
            for (int ntl = 0; ntl < 4; ntl++) {
                int n = nbase + ntl * 16 + col;
                float v0 = fmaxf(acc1[ftl][ntl][0], 0.f);
                float v1 = fmaxf(acc1[ftl][ntl][1], 0.f);
                float v2 = fmaxf(acc1[ftl][ntl][2], 0.f);
                float v3 = fmaxf(acc1[ftl][ntl][3], 0.f);
                u32 lo = (u32)f2bf(v0) | ((u32)f2bf(v1) << 16);
                u32 hi = (u32)f2bf(v2) | ((u32)f2bf(v3) << 16);
                *(uint2*)&sZ[n * 136 + f] = make_uint2(lo, hi);
            }
        }
        __syncthreads();                 // S3: z1 ready
        // --- GEMM2: D[feature][node] = W2^T (A) x z1^T (B); B-frags contiguous b128 ---
        short8 aw2[2][4];
#pragma unroll
        for (int ftl = 0; ftl < 2; ftl++) {
            int ft = ((w & 3) << 1) + ftl;
#pragma unroll
            for (int kc = 0; kc < 4; kc++)
                aw2[ftl][kc] = *(const short8*)&sB2[(((ft << 2) + kc) << 6 | (lane ^ (kc << 1))) * 8];
        }
        short8 bz[4][4];
#pragma unroll
        for (int ntl = 0; ntl < 4; ntl++) {
            int n = nbase + ntl * 16 + col;
#pragma unroll
            for (int kc = 0; kc < 4; kc++) {
                int k0 = kc * 32 + fq * 8;
                bz[ntl][kc] = *(const short8*)&sZ[n * 136 + k0];
            }
        }
        f32x4 acc2[2][4];
#pragma unroll
        for (int ftl = 0; ftl < 2; ftl++)
#pragma unroll
            for (int ntl = 0; ntl < 4; ntl++) {
                acc2[ftl][ntl][0] = bias2v[ftl].x; acc2[ftl][ntl][1] = bias2v[ftl].y;
                acc2[ftl][ntl][2] = bias2v[ftl].z; acc2[ftl][ntl][3] = bias2v[ftl].w;
            }
#pragma unroll
        for (int ntl = 0; ntl < 4; ntl++)
#pragma unroll
            for (int kc = 0; kc < 4; kc++) {
                acc2[0][ntl] = __builtin_amdgcn_mfma_f32_16x16x32_bf16(aw2[0][kc], bz[ntl][kc], acc2[0][ntl], 0, 0, 0);
                acc2[1][ntl] = __builtin_amdgcn_mfma_f32_16x16x32_bf16(aw2[1][kc], bz[ntl][kc], acc2[1][ntl], 0, 0, 0);
            }
        __syncthreads();                 // S4: all sZ reads complete
        // --- stage acc2 -> sZ row-major via b64 ---
#pragma unroll
        for (int ftl = 0; ftl < 2; ftl++) {
            int f = fbase + ftl * 16 + fq * 4;
#pragma unroll
            for (int ntl = 0; ntl < 4; ntl++) {
                int n = nbase + ntl * 16 + col;
                u32 lo = (u32)f2bf(acc2[ftl][ntl][0]) | ((u32)f2bf(acc2[ftl][ntl][1]) << 16);
                u32 hi = (u32)f2bf(acc2[ftl][ntl][2]) | ((u32)f2bf(acc2[ftl][ntl][3]) << 16);
                *(uint2*)&sZ[n * 136 + f] = make_uint2(lo, hi);
            }
        }
        __syncthreads();                 // S5
#pragma unroll
        for (int i = 0; i < 4; i++) {
            int c = t + 512 * i;
            int n = c >> 4, k8 = c & 15;
            if (n < nvalid)
                *(uint4*)&out[((size_t)(base + n)) * HD + k8 * 8] =
                    *(const uint4*)&sZ[n * 136 + k8 * 8];
        }
    }
}

// ---------------- per-graph sum pool (bf16 in, fp32 atomics out) ----------------
__global__ __launch_bounds__(64) void pool_kernel(const u16* __restrict__ h,
                                                  const int* __restrict__ gid,
                                                  float* __restrict__ out, int N) {
    const int CH = 32;
    int j = threadIdx.x;
    int start = blockIdx.x * CH;
    if (start >= N) return;
    int end = min(start + CH, N);
    int cur = gid[start];
    float x0 = 0.f, x1 = 0.f;
    for (int n = start; n < end; n++) {
        int g = gid[n];
        if (g != cur) {
            atomicAdd(&out[(size_t)cur * HD + 2 * j], x0);
            atomicAdd(&out[(size_t)cur * HD + 2 * j + 1], x1);
            cur = g; x0 = 0.f; x1 = 0.f;
        }
        u32 v = *(const u32*)&h[(size_t)n * HD + j * 2];
        x0 += bfLo(v); x1 += bfHi(v);
    }
    atomicAdd(&out[(size_t)cur * HD + 2 * j], x0);
    atomicAdd(&out[(size_t)cur * HD + 2 * j + 1], x1);
}

extern "C" void kernel_launch(void* const* d_in, const int* in_sizes, int n_in,
                              void* d_out, int out_size, void* d_ws, size_t ws_size,
                              hipStream_t stream) {
    (void)n_in; (void)ws_size;
    const float* x   = (const float*)d_in[0];
    const float* Wfc = (const float*)d_in[1];
    const float* bfc = (const float*)d_in[2];
    const float* W1  = (const float*)d_in[3];
    const float* b1  = (const float*)d_in[4];
    const float* W2  = (const float*)d_in[5];
    const float* b2  = (const float*)d_in[6];
    const int* src   = (const int*)d_in[7];
    const int* dst   = (const int*)d_in[8];
    const int* gid   = (const int*)d_in[9];

    int N = in_sizes[0] / DIN;       // 100000
    int E = in_sizes[7];             // 1600000
    int nTiles = (N + 127) / 128;
    int nB = (E + EB - 1) / EB;      // partition blocks (196)
    int nScan2 = NBKT * nB;          // histT length
    int nb2 = (nScan2 + 1023) / 1024;

    // workspace layout (~65 MB)
    u16* h = (u16*)d_ws;                          // N*128 bf16
    u16* z = h + (size_t)N * HD;                  // N*128 bf16
    int* off    = (int*)(z + (size_t)N * HD);     // N+1
    int* esrc   = off + (N + 1);                  // E
    int* bsums2 = esrc + E;                       // 256
    int* histT  = bsums2 + 256;                   // NBKT*nB
    u32* bpairs = (u32*)(histT + nScan2);         // E packed pairs

    // --- radix partition of edges by dst>>8 (no global atomics) ---
    rhist_kernel<<<nB, 256, 0, stream>>>(dst, histT, E, nB);
    scan1_kernel<<<nb2, 256, 0, stream>>>(histT, bsums2, nScan2);
    scan2_kernel<<<1, 1024, 0, stream>>>(bsums2, nb2);
    scan3_kernel<<<(nScan2 + 255) / 256, 256, 0, stream>>>(histT, bsums2, nScan2);
    rpos_kernel<<<nB, 256, 0, stream>>>(src, dst, histT, bpairs, E, nB);

    // --- fused per-node CSR offsets + scatter (per-bucket, LDS only) ---
    bfinal_kernel<<<NBKT, 256, 0, stream>>>(bpairs, histT, off, esrc, N, nB);

    // --- node projection (bf16 out) ---
    fc_kernel<<<512, 512, 0, stream>>>(x, Wfc, bfc, h, N, nTiles);

    // --- 3x GINConv (standalone agg for max wave-parallelism + R8 MLP pair) ---
    for (int l = 0; l < 3; l++) {
        agg_kernel<<<(N + 3) / 4, 256, 0, stream>>>(h, off, esrc, z, N);
        mlp_pair_kernel<<<256, 512, 0, stream>>>(z, W1 + (size_t)l * HD * HD,
                                                 b1 + (size_t)l * HD,
                                                 W2 + (size_t)l * HD * HD,
                                                 b2 + (size_t)l * HD, h, N, nTiles);
    }

    // --- per-graph sum pooling ---
    zero_f32_kernel<<<(out_size + 255) / 256, 256, 0, stream>>>((float*)d_out, out_size);
    pool_kernel<<<(N + 31) / 32, 64, 0, stream>>>(h, gid, (float*)d_out, N);
}